// Round 2
// baseline (348.849 us; speedup 1.0000x reference)
//
#include <hip/hip_runtime.h>
#include <hip/hip_bf16.h>

// RAYEN ConstraintModule fused kernel for MI355X (gfx950).
// B=32768, IN_DIM=256, N=K=128, M_LIN=1024, QC=16. bf16 buffers (detector-routed).
// R1: 32-row tiles x 1024 WGs (4 blocks/CU, 16 waves/CU), batched+double-buffered
// B-operand streaming, rho aliased onto x LDS, coalesced 16B epilogue stores.

typedef __attribute__((ext_vector_type(8))) short short8;
typedef __attribute__((ext_vector_type(4))) float f32x4;

__device__ __forceinline__ float bf2f(unsigned short u) {
    union { unsigned int i; float f; } v; v.i = ((unsigned int)u) << 16; return v.f;
}
__device__ __forceinline__ unsigned short f2bf(float f) {
    union { float f; unsigned int i; } v; v.f = f;
    unsigned int r = v.i + 0x7FFFu + ((v.i >> 16) & 1u);  // RNE
    return (unsigned short)(r >> 16);
}

template<int DT>
__device__ __forceinline__ short8 ld8(const void* p, long i) {
    if constexpr (DT == 1) {
        return *reinterpret_cast<const short8*>(reinterpret_cast<const unsigned short*>(p) + i);
    } else {
        const float* f = reinterpret_cast<const float*>(p) + i;
        short8 r;
#pragma unroll
        for (int j = 0; j < 8; ++j) r[j] = (short)f2bf(f[j]);
        return r;
    }
}
template<int DT>
__device__ __forceinline__ float ldf(const void* p, int i) {
    if constexpr (DT == 1) return bf2f(reinterpret_cast<const unsigned short*>(p)[i]);
    else return reinterpret_cast<const float*>(p)[i];
}

__global__ void detect_dtype(const unsigned short* __restrict__ x, int* __restrict__ flag) {
    __shared__ int cnt;
    if (threadIdx.x == 0) cnt = 0;
    __syncthreads();
    float a = fabsf(bf2f(x[threadIdx.x]));
    int ok = (a > 1e-3f && a < 1e2f) ? 1 : 0;
    atomicAdd(&cnt, ok);
    __syncthreads();
    if (threadIdx.x == 0) *flag = (cnt > 200) ? 1 : 0;  // 1 = bf16, 0 = f32
}

template<int DT>
__global__ __launch_bounds__(256, 4) void rayen_fused(
    const void* __restrict__ xp,   const void* __restrict__ Wp,
    const void* __restrict__ bp,   const void* __restrict__ Dp,
    const void* __restrict__ ypp,  const void* __restrict__ z0p,
    const void* __restrict__ phip, const void* __restrict__ dltp,
    void* __restrict__ outp,       const int* __restrict__ flag)
{
    if (*flag != DT) return;

    __shared__ unsigned char lds_x[32 * 512];   // x tile; first 8KB later reused for rho
    unsigned char* lds_rho = lds_x;             // rho [32][256B], alias (x dead by then)
    __shared__ float lds_nsq[32][4];
    __shared__ float lds_dmax[32][4];
    __shared__ float lds_quad[32][16];
    __shared__ float lds_lin[32][16];
    __shared__ float lds_alpha[32];

    const int tid = threadIdx.x;
    const int lane = tid & 63;
    const int w = tid >> 6;        // wave 0..3
    const int hi = lane >> 4;      // 0..3
    const int lo = lane & 15;      // 0..15
    const long row0 = (long)blockIdx.x * 32;

    // ---- stage x tile [32][256] bf16, XOR-swizzled 512B rows ----
#pragma unroll
    for (int t = 0; t < 4; ++t) {
        int chunk = tid + t * 256;
        int L = chunk * 16;
        int r = L >> 9;
        int off = L & 511;
        int c2 = off ^ ((r & 7) << 4);
        short8 v = ld8<DT>(xp, row0 * 256 + r * 256 + (c2 >> 1));
        *reinterpret_cast<short8*>(lds_x + L) = v;
    }
    __syncthreads();

    // ---- GEMM1: v[32][128] = x @ W^T; wave w: cols [w*32, w*32+32) ----
    f32x4 acc1[2][2];
#pragma unroll
    for (int c = 0; c < 2; ++c)
#pragma unroll
        for (int r = 0; r < 2; ++r)
#pragma unroll
            for (int e = 0; e < 4; ++e) acc1[c][r][e] = 0.f;

#pragma unroll
    for (int kb = 0; kb < 8; ++kb) {
        short8 af[2];
#pragma unroll
        for (int rt = 0; rt < 2; ++rt) {
            int row = rt * 16 + lo;
            af[rt] = *reinterpret_cast<const short8*>(
                lds_x + row * 512 + ((kb * 64 + hi * 16) ^ ((row & 7) << 4)));
        }
#pragma unroll
        for (int ct = 0; ct < 2; ++ct) {
            int col = w * 32 + ct * 16 + lo;
            short8 bw = ld8<DT>(Wp, (long)col * 256 + kb * 32 + hi * 8);
#pragma unroll
            for (int rt = 0; rt < 2; ++rt)
                acc1[ct][rt] = __builtin_amdgcn_mfma_f32_16x16x32_bf16(af[rt], bw, acc1[ct][rt], 0, 0, 0);
        }
    }

    float bv[2];
#pragma unroll
    for (int ct = 0; ct < 2; ++ct) bv[ct] = ldf<DT>(bp, w * 32 + ct * 16 + lo);
#pragma unroll
    for (int rt = 0; rt < 2; ++rt)
#pragma unroll
        for (int reg = 0; reg < 4; ++reg) {
            float s = 0.f;
#pragma unroll
            for (int ct = 0; ct < 2; ++ct) {
                float v = acc1[ct][rt][reg] + bv[ct];
                acc1[ct][rt][reg] = v;
                s += v * v;
            }
            s += __shfl_xor(s, 1);
            s += __shfl_xor(s, 2);
            s += __shfl_xor(s, 4);
            s += __shfl_xor(s, 8);
            if (lo == 0) lds_nsq[rt * 16 + hi * 4 + reg][w] = s;
        }
    __syncthreads();   // all x reads done; rho may overwrite x region

    // ---- v_bar -> swizzled bf16 LDS (aliased) ----
#pragma unroll
    for (int rt = 0; rt < 2; ++rt)
#pragma unroll
        for (int reg = 0; reg < 4; ++reg) {
            int row = rt * 16 + hi * 4 + reg;
            float nsq = lds_nsq[row][0] + lds_nsq[row][1] + lds_nsq[row][2] + lds_nsq[row][3];
            float rinv = 1.0f / fmaxf(sqrtf(nsq), 1e-12f);
#pragma unroll
            for (int ct = 0; ct < 2; ++ct) {
                int col = w * 32 + ct * 16 + lo;
                unsigned short u = f2bf(acc1[ct][rt][reg] * rinv);
                *reinterpret_cast<unsigned short*>(
                    lds_rho + row * 256 + ((col * 2) ^ ((row & 7) << 4))) = u;
            }
        }
    __syncthreads();

    // ---- A-fragments (rho) resident in registers: 32 VGPRs ----
    short8 af2[2][4];
#pragma unroll
    for (int rt = 0; rt < 2; ++rt)
#pragma unroll
        for (int kb = 0; kb < 4; ++kb) {
            int row = rt * 16 + lo;
            af2[rt][kb] = *reinterpret_cast<const short8*>(
                lds_rho + row * 256 + ((kb * 64 + hi * 16) ^ ((row & 7) << 4)));
        }

    // ---- D segment: wave w cols [w*256,(w+1)*256); dbl-buffered batched loads ----
    f32x4 dmax[2];
#pragma unroll
    for (int rt = 0; rt < 2; ++rt)
#pragma unroll
        for (int e = 0; e < 4; ++e) dmax[rt][e] = -3e38f;

    short8 bD[2][4];
    {
        int col = w * 256 + lo;
#pragma unroll
        for (int kb = 0; kb < 4; ++kb)
            bD[0][kb] = ld8<DT>(Dp, (long)col * 128 + kb * 32 + hi * 8);
    }
#pragma unroll
    for (int t = 0; t < 16; ++t) {
        int cur = t & 1;
        if (t < 15) {
            int col = w * 256 + (t + 1) * 16 + lo;
#pragma unroll
            for (int kb = 0; kb < 4; ++kb)
                bD[cur ^ 1][kb] = ld8<DT>(Dp, (long)col * 128 + kb * 32 + hi * 8);
        }
        f32x4 acc[2];
#pragma unroll
        for (int rt = 0; rt < 2; ++rt)
#pragma unroll
            for (int e = 0; e < 4; ++e) acc[rt][e] = 0.f;
#pragma unroll
        for (int kb = 0; kb < 4; ++kb)
#pragma unroll
            for (int rt = 0; rt < 2; ++rt)
                acc[rt] = __builtin_amdgcn_mfma_f32_16x16x32_bf16(af2[rt][kb], bD[cur][kb], acc[rt], 0, 0, 0);
#pragma unroll
        for (int rt = 0; rt < 2; ++rt)
#pragma unroll
            for (int e = 0; e < 4; ++e) dmax[rt][e] = fmaxf(dmax[rt][e], acc[rt][e]);
    }
#pragma unroll
    for (int rt = 0; rt < 2; ++rt)
#pragma unroll
        for (int reg = 0; reg < 4; ++reg) {
            float m = dmax[rt][reg];
            m = fmaxf(m, __shfl_xor(m, 1));
            m = fmaxf(m, __shfl_xor(m, 2));
            m = fmaxf(m, __shfl_xor(m, 4));
            m = fmaxf(m, __shfl_xor(m, 8));
            if (lo == 0) lds_dmax[rt * 16 + hi * 4 + reg][w] = m;
        }

    // ---- delta segment: wave w owns q in [4w,4w+4); flattened (t,q) pipeline ----
    f32x4 qsum[4][2];
#pragma unroll
    for (int q = 0; q < 4; ++q)
#pragma unroll
        for (int rt = 0; rt < 2; ++rt)
#pragma unroll
            for (int e = 0; e < 4; ++e) qsum[q][rt][e] = 0.f;

    float rv[2][4];
    short8 bq[2][4];
    {
        int qg = w * 4, colk = lo;
#pragma unroll
        for (int kb = 0; kb < 4; ++kb)
            bq[0][kb] = ld8<DT>(dltp, ((long)qg * 128 + colk) * 128 + kb * 32 + hi * 8);
    }
#pragma unroll
    for (int s = 0; s < 32; ++s) {
        int t = s >> 2, ql = s & 3, cur = s & 1;
        if (ql == 0) {
#pragma unroll
            for (int rt = 0; rt < 2; ++rt)
#pragma unroll
                for (int reg = 0; reg < 4; ++reg) {
                    int row = rt * 16 + hi * 4 + reg;
                    int colk = t * 16 + lo;
                    rv[rt][reg] = bf2f(*reinterpret_cast<const unsigned short*>(
                        lds_rho + row * 256 + ((colk * 2) ^ ((row & 7) << 4))));
                }
        }
        if (s < 31) {
            int s2 = s + 1;
            int qg2 = w * 4 + (s2 & 3);
            int colk2 = (s2 >> 2) * 16 + lo;
#pragma unroll
            for (int kb = 0; kb < 4; ++kb)
                bq[cur ^ 1][kb] = ld8<DT>(dltp, ((long)qg2 * 128 + colk2) * 128 + kb * 32 + hi * 8);
        }
        f32x4 acc[2];
#pragma unroll
        for (int rt = 0; rt < 2; ++rt)
#pragma unroll
            for (int e = 0; e < 4; ++e) acc[rt][e] = 0.f;
#pragma unroll
        for (int kb = 0; kb < 4; ++kb)
#pragma unroll
            for (int rt = 0; rt < 2; ++rt)
                acc[rt] = __builtin_amdgcn_mfma_f32_16x16x32_bf16(af2[rt][kb], bq[cur][kb], acc[rt], 0, 0, 0);
#pragma unroll
        for (int rt = 0; rt < 2; ++rt)
#pragma unroll
            for (int e = 0; e < 4; ++e) qsum[ql][rt][e] += acc[rt][e] * rv[rt][e];
    }
#pragma unroll
    for (int ql = 0; ql < 4; ++ql)
#pragma unroll
        for (int rt = 0; rt < 2; ++rt)
#pragma unroll
            for (int reg = 0; reg < 4; ++reg) {
                float s = qsum[ql][rt][reg];
                s += __shfl_xor(s, 1);
                s += __shfl_xor(s, 2);
                s += __shfl_xor(s, 4);
                s += __shfl_xor(s, 8);
                if (lo == 0) lds_quad[rt * 16 + hi * 4 + reg][w * 4 + ql] = s;
            }

    // ---- phi segment (wave 0): lin[b,q] = rho . phi_q ----
    if (w == 0) {
        f32x4 acc[2];
#pragma unroll
        for (int rt = 0; rt < 2; ++rt)
#pragma unroll
            for (int e = 0; e < 4; ++e) acc[rt][e] = 0.f;
#pragma unroll
        for (int kb = 0; kb < 4; ++kb) {
            short8 bp8 = ld8<DT>(phip, (long)lo * 128 + kb * 32 + hi * 8);
#pragma unroll
            for (int rt = 0; rt < 2; ++rt)
                acc[rt] = __builtin_amdgcn_mfma_f32_16x16x32_bf16(af2[rt][kb], bp8, acc[rt], 0, 0, 0);
        }
#pragma unroll
        for (int rt = 0; rt < 2; ++rt)
#pragma unroll
            for (int reg = 0; reg < 4; ++reg)
                lds_lin[rt * 16 + hi * 4 + reg][lo] = acc[rt][reg];
    }
    __syncthreads();

    // ---- per-row scalars: kappa, alpha ----
    if (tid < 32) {
        int row = tid;
        float nsq = lds_nsq[row][0] + lds_nsq[row][1] + lds_nsq[row][2] + lds_nsq[row][3];
        float norm = sqrtf(nsq);
        float kap = fmaxf(0.f, fmaxf(fmaxf(lds_dmax[row][0], lds_dmax[row][1]),
                                     fmaxf(lds_dmax[row][2], lds_dmax[row][3])));
#pragma unroll
        for (int q = 0; q < 16; ++q) {
            float kq = lds_lin[row][q] + sqrtf(fmaxf(lds_quad[row][q], 0.f));
            kap = fmaxf(kap, kq);
        }
        lds_alpha[row] = fminf(1.0f / kap, norm);
    }
    __syncthreads();

    // ---- coalesced epilogue: y = z0 + alpha * v_bar + yp ----
#pragma unroll
    for (int i = 0; i < 2; ++i) {
        int idx = tid + i * 256;
        int row = idx >> 4;
        int col0 = (idx & 15) * 8;
        float alpha = lds_alpha[row];
        short8 r8 = *reinterpret_cast<const short8*>(
            lds_rho + row * 256 + ((col0 * 2) ^ ((row & 7) << 4)));
        float yv[8];
#pragma unroll
        for (int j = 0; j < 8; ++j) {
            float vb = bf2f((unsigned short)r8[j]);
            yv[j] = ldf<DT>(z0p, col0 + j) + alpha * vb + ldf<DT>(ypp, col0 + j);
        }
        long obase = (row0 + row) * 128 + col0;
        if constexpr (DT == 1) {
            short8 pack;
#pragma unroll
            for (int j = 0; j < 8; ++j) pack[j] = (short)f2bf(yv[j]);
            *reinterpret_cast<short8*>(reinterpret_cast<unsigned short*>(outp) + obase) = pack;
        } else {
            f32x4 p0, p1;
#pragma unroll
            for (int j = 0; j < 4; ++j) { p0[j] = yv[j]; p1[j] = yv[4 + j]; }
            *reinterpret_cast<f32x4*>(reinterpret_cast<float*>(outp) + obase) = p0;
            *reinterpret_cast<f32x4*>(reinterpret_cast<float*>(outp) + obase + 4) = p1;
        }
    }
}

extern "C" void kernel_launch(void* const* d_in, const int* in_sizes, int n_in,
                              void* d_out, int out_size, void* d_ws, size_t ws_size,
                              hipStream_t stream) {
    const void* x    = d_in[0];
    const void* W    = d_in[1];
    const void* b    = d_in[2];
    const void* D    = d_in[3];
    // d_in[4] = NA_E (identity by construction; unused)
    const void* yp   = d_in[5];
    const void* z0   = d_in[6];
    const void* phi  = d_in[7];
    const void* dlt  = d_in[8];
    int* flag = reinterpret_cast<int*>(d_ws);

    const int B = in_sizes[0] / 256;    // 32768
    dim3 grid(B / 32), blk(256);

    detect_dtype<<<dim3(1), dim3(256), 0, stream>>>(
        reinterpret_cast<const unsigned short*>(x), flag);
    rayen_fused<1><<<grid, blk, 0, stream>>>(x, W, b, D, yp, z0, phi, dlt, d_out, flag);
    rayen_fused<0><<<grid, blk, 0, stream>>>(x, W, b, D, yp, z0, phi, dlt, d_out, flag);
}

// Round 3
// 346.908 us; speedup vs baseline: 1.0056x; 1.0056x over previous
//
#include <hip/hip_runtime.h>
#include <hip/hip_bf16.h>

// RAYEN ConstraintModule fused kernel for MI355X (gfx950).
// B=32768, IN_DIM=256, N=K=128, M_LIN=1024, QC=16. bf16 buffers (detector-routed).
// R2: back to launch_bounds(256,2) (R1's (256,4) caused 64-reg cap -> scratch spills,
// 393MB writes). 64-row tiles x 512 WGs, rt=4, double-buffered batched B prefetch,
// rho aliased onto x LDS, coalesced 16B epilogue stores.

typedef __attribute__((ext_vector_type(8))) short short8;
typedef __attribute__((ext_vector_type(4))) float f32x4;

__device__ __forceinline__ float bf2f(unsigned short u) {
    union { unsigned int i; float f; } v; v.i = ((unsigned int)u) << 16; return v.f;
}
__device__ __forceinline__ unsigned short f2bf(float f) {
    union { float f; unsigned int i; } v; v.f = f;
    unsigned int r = v.i + 0x7FFFu + ((v.i >> 16) & 1u);  // RNE
    return (unsigned short)(r >> 16);
}

template<int DT>
__device__ __forceinline__ short8 ld8(const void* p, long i) {
    if constexpr (DT == 1) {
        return *reinterpret_cast<const short8*>(reinterpret_cast<const unsigned short*>(p) + i);
    } else {
        const float* f = reinterpret_cast<const float*>(p) + i;
        short8 r;
#pragma unroll
        for (int j = 0; j < 8; ++j) r[j] = (short)f2bf(f[j]);
        return r;
    }
}
template<int DT>
__device__ __forceinline__ float ldf(const void* p, int i) {
    if constexpr (DT == 1) return bf2f(reinterpret_cast<const unsigned short*>(p)[i]);
    else return reinterpret_cast<const float*>(p)[i];
}

__global__ void detect_dtype(const unsigned short* __restrict__ x, int* __restrict__ flag) {
    __shared__ int cnt;
    if (threadIdx.x == 0) cnt = 0;
    __syncthreads();
    float a = fabsf(bf2f(x[threadIdx.x]));
    int ok = (a > 1e-3f && a < 1e2f) ? 1 : 0;
    atomicAdd(&cnt, ok);
    __syncthreads();
    if (threadIdx.x == 0) *flag = (cnt > 200) ? 1 : 0;  // 1 = bf16, 0 = f32
}

template<int DT>
__global__ __launch_bounds__(256, 2) void rayen_fused(
    const void* __restrict__ xp,   const void* __restrict__ Wp,
    const void* __restrict__ bp,   const void* __restrict__ Dp,
    const void* __restrict__ ypp,  const void* __restrict__ z0p,
    const void* __restrict__ phip, const void* __restrict__ dltp,
    void* __restrict__ outp,       const int* __restrict__ flag)
{
    if (*flag != DT) return;

    __shared__ unsigned char lds_x[64 * 512];   // x tile [64][256] bf16, swizzled 512B rows
    unsigned char* lds_rho = lds_x;             // rho [64][256B] aliased (x dead by then)
    __shared__ float lds_nsq[64][4];
    __shared__ float lds_dmax[64][4];
    __shared__ float lds_quad[64][16];
    __shared__ float lds_lin[64][16];
    __shared__ float lds_alpha[64];

    const int tid = threadIdx.x;
    const int lane = tid & 63;
    const int w = tid >> 6;        // wave 0..3
    const int hi = lane >> 4;      // 0..3
    const int lo = lane & 15;      // 0..15
    const long row0 = (long)blockIdx.x * 64;

    // ---- stage x tile, XOR-swizzled ----
#pragma unroll
    for (int t = 0; t < 8; ++t) {
        int chunk = tid + t * 256;
        int L = chunk * 16;
        int r = L >> 9;
        int off = L & 511;
        int c2 = off ^ ((r & 7) << 4);
        short8 v = ld8<DT>(xp, row0 * 256 + r * 256 + (c2 >> 1));
        *reinterpret_cast<short8*>(lds_x + L) = v;
    }
    __syncthreads();

    // ---- GEMM1: v[64][128] = x @ W^T; wave w: cols [w*32, w*32+32) ----
    f32x4 acc1[2][4];
#pragma unroll
    for (int c = 0; c < 2; ++c)
#pragma unroll
        for (int r = 0; r < 4; ++r)
#pragma unroll
            for (int e = 0; e < 4; ++e) acc1[c][r][e] = 0.f;

#pragma unroll
    for (int kb = 0; kb < 8; ++kb) {
        short8 af[4];
#pragma unroll
        for (int rt = 0; rt < 4; ++rt) {
            int row = rt * 16 + lo;
            af[rt] = *reinterpret_cast<const short8*>(
                lds_x + row * 512 + ((kb * 64 + hi * 16) ^ ((row & 7) << 4)));
        }
#pragma unroll
        for (int ct = 0; ct < 2; ++ct) {
            int col = w * 32 + ct * 16 + lo;
            short8 bw = ld8<DT>(Wp, (long)col * 256 + kb * 32 + hi * 8);
#pragma unroll
            for (int rt = 0; rt < 4; ++rt)
                acc1[ct][rt] = __builtin_amdgcn_mfma_f32_16x16x32_bf16(af[rt], bw, acc1[ct][rt], 0, 0, 0);
        }
    }

    float bv[2];
#pragma unroll
    for (int ct = 0; ct < 2; ++ct) bv[ct] = ldf<DT>(bp, w * 32 + ct * 16 + lo);
#pragma unroll
    for (int rt = 0; rt < 4; ++rt)
#pragma unroll
        for (int reg = 0; reg < 4; ++reg) {
            float s = 0.f;
#pragma unroll
            for (int ct = 0; ct < 2; ++ct) {
                float v = acc1[ct][rt][reg] + bv[ct];
                acc1[ct][rt][reg] = v;
                s += v * v;
            }
            s += __shfl_xor(s, 1);
            s += __shfl_xor(s, 2);
            s += __shfl_xor(s, 4);
            s += __shfl_xor(s, 8);
            if (lo == 0) lds_nsq[rt * 16 + hi * 4 + reg][w] = s;
        }
    __syncthreads();   // all x reads done; rho may overwrite x region

    // ---- v_bar -> swizzled bf16 LDS (aliased over x) ----
#pragma unroll
    for (int rt = 0; rt < 4; ++rt)
#pragma unroll
        for (int reg = 0; reg < 4; ++reg) {
            int row = rt * 16 + hi * 4 + reg;
            float nsq = lds_nsq[row][0] + lds_nsq[row][1] + lds_nsq[row][2] + lds_nsq[row][3];
            float rinv = 1.0f / fmaxf(sqrtf(nsq), 1e-12f);
#pragma unroll
            for (int ct = 0; ct < 2; ++ct) {
                int col = w * 32 + ct * 16 + lo;
                unsigned short u = f2bf(acc1[ct][rt][reg] * rinv);
                *reinterpret_cast<unsigned short*>(
                    lds_rho + row * 256 + ((col * 2) ^ ((row & 7) << 4))) = u;
            }
        }
    __syncthreads();

    // ---- A-fragments (rho) resident in registers: 64 VGPRs ----
    short8 af2[4][4];
#pragma unroll
    for (int rt = 0; rt < 4; ++rt)
#pragma unroll
        for (int kb = 0; kb < 4; ++kb) {
            int row = rt * 16 + lo;
            af2[rt][kb] = *reinterpret_cast<const short8*>(
                lds_rho + row * 256 + ((kb * 64 + hi * 16) ^ ((row & 7) << 4)));
        }

    // ---- D segment: wave w cols [w*256,(w+1)*256); dbl-buffered batched loads ----
    f32x4 dmax[4];
#pragma unroll
    for (int rt = 0; rt < 4; ++rt)
#pragma unroll
        for (int e = 0; e < 4; ++e) dmax[rt][e] = -3e38f;

    short8 bD[2][4];
    {
        int col = w * 256 + lo;
#pragma unroll
        for (int kb = 0; kb < 4; ++kb)
            bD[0][kb] = ld8<DT>(Dp, (long)col * 128 + kb * 32 + hi * 8);
    }
#pragma unroll
    for (int t = 0; t < 16; ++t) {
        int cur = t & 1;
        if (t < 15) {
            int col = w * 256 + (t + 1) * 16 + lo;
#pragma unroll
            for (int kb = 0; kb < 4; ++kb)
                bD[cur ^ 1][kb] = ld8<DT>(Dp, (long)col * 128 + kb * 32 + hi * 8);
        }
        f32x4 acc[4];
#pragma unroll
        for (int rt = 0; rt < 4; ++rt)
#pragma unroll
            for (int e = 0; e < 4; ++e) acc[rt][e] = 0.f;
#pragma unroll
        for (int kb = 0; kb < 4; ++kb)
#pragma unroll
            for (int rt = 0; rt < 4; ++rt)
                acc[rt] = __builtin_amdgcn_mfma_f32_16x16x32_bf16(af2[rt][kb], bD[cur][kb], acc[rt], 0, 0, 0);
#pragma unroll
        for (int rt = 0; rt < 4; ++rt)
#pragma unroll
            for (int e = 0; e < 4; ++e) dmax[rt][e] = fmaxf(dmax[rt][e], acc[rt][e]);
    }
#pragma unroll
    for (int rt = 0; rt < 4; ++rt)
#pragma unroll
        for (int reg = 0; reg < 4; ++reg) {
            float m = dmax[rt][reg];
            m = fmaxf(m, __shfl_xor(m, 1));
            m = fmaxf(m, __shfl_xor(m, 2));
            m = fmaxf(m, __shfl_xor(m, 4));
            m = fmaxf(m, __shfl_xor(m, 8));
            if (lo == 0) lds_dmax[rt * 16 + hi * 4 + reg][w] = m;
        }

    // ---- delta segment: wave w owns q in [4w,4w+4); flattened (t,q) pipeline ----
    f32x4 qsum[4][4];
#pragma unroll
    for (int q = 0; q < 4; ++q)
#pragma unroll
        for (int rt = 0; rt < 4; ++rt)
#pragma unroll
            for (int e = 0; e < 4; ++e) qsum[q][rt][e] = 0.f;

    float rv[4][4];
    short8 bq[2][4];
    {
        int qg = w * 4, colk = lo;
#pragma unroll
        for (int kb = 0; kb < 4; ++kb)
            bq[0][kb] = ld8<DT>(dltp, ((long)qg * 128 + colk) * 128 + kb * 32 + hi * 8);
    }
#pragma unroll
    for (int s = 0; s < 32; ++s) {
        int t = s >> 2, ql = s & 3, cur = s & 1;
        if (ql == 0) {
#pragma unroll
            for (int rt = 0; rt < 4; ++rt)
#pragma unroll
                for (int reg = 0; reg < 4; ++reg) {
                    int row = rt * 16 + hi * 4 + reg;
                    int colk = t * 16 + lo;
                    rv[rt][reg] = bf2f(*reinterpret_cast<const unsigned short*>(
                        lds_rho + row * 256 + ((colk * 2) ^ ((row & 7) << 4))));
                }
        }
        if (s < 31) {
            int s2 = s + 1;
            int qg2 = w * 4 + (s2 & 3);
            int colk2 = (s2 >> 2) * 16 + lo;
#pragma unroll
            for (int kb = 0; kb < 4; ++kb)
                bq[cur ^ 1][kb] = ld8<DT>(dltp, ((long)qg2 * 128 + colk2) * 128 + kb * 32 + hi * 8);
        }
        f32x4 acc[4];
#pragma unroll
        for (int rt = 0; rt < 4; ++rt)
#pragma unroll
            for (int e = 0; e < 4; ++e) acc[rt][e] = 0.f;
#pragma unroll
        for (int kb = 0; kb < 4; ++kb)
#pragma unroll
            for (int rt = 0; rt < 4; ++rt)
                acc[rt] = __builtin_amdgcn_mfma_f32_16x16x32_bf16(af2[rt][kb], bq[cur][kb], acc[rt], 0, 0, 0);
#pragma unroll
        for (int rt = 0; rt < 4; ++rt)
#pragma unroll
            for (int e = 0; e < 4; ++e) qsum[ql][rt][e] += acc[rt][e] * rv[rt][e];
    }
#pragma unroll
    for (int ql = 0; ql < 4; ++ql)
#pragma unroll
        for (int rt = 0; rt < 4; ++rt)
#pragma unroll
            for (int reg = 0; reg < 4; ++reg) {
                float s = qsum[ql][rt][reg];
                s += __shfl_xor(s, 1);
                s += __shfl_xor(s, 2);
                s += __shfl_xor(s, 4);
                s += __shfl_xor(s, 8);
                if (lo == 0) lds_quad[rt * 16 + hi * 4 + reg][w * 4 + ql] = s;
            }

    // ---- phi segment (wave 0): lin[b,q] = rho . phi_q ----
    if (w == 0) {
        f32x4 acc[4];
#pragma unroll
        for (int rt = 0; rt < 4; ++rt)
#pragma unroll
            for (int e = 0; e < 4; ++e) acc[rt][e] = 0.f;
#pragma unroll
        for (int kb = 0; kb < 4; ++kb) {
            short8 bp8 = ld8<DT>(phip, (long)lo * 128 + kb * 32 + hi * 8);
#pragma unroll
            for (int rt = 0; rt < 4; ++rt)
                acc[rt] = __builtin_amdgcn_mfma_f32_16x16x32_bf16(af2[rt][kb], bp8, acc[rt], 0, 0, 0);
        }
#pragma unroll
        for (int rt = 0; rt < 4; ++rt)
#pragma unroll
            for (int reg = 0; reg < 4; ++reg)
                lds_lin[rt * 16 + hi * 4 + reg][lo] = acc[rt][reg];
    }
    __syncthreads();

    // ---- per-row scalars: kappa, alpha ----
    if (tid < 64) {
        int row = tid;
        float nsq = lds_nsq[row][0] + lds_nsq[row][1] + lds_nsq[row][2] + lds_nsq[row][3];
        float norm = sqrtf(nsq);
        float kap = fmaxf(0.f, fmaxf(fmaxf(lds_dmax[row][0], lds_dmax[row][1]),
                                     fmaxf(lds_dmax[row][2], lds_dmax[row][3])));
#pragma unroll
        for (int q = 0; q < 16; ++q) {
            float kq = lds_lin[row][q] + sqrtf(fmaxf(lds_quad[row][q], 0.f));
            kap = fmaxf(kap, kq);
        }
        lds_alpha[row] = fminf(1.0f / kap, norm);
    }
    __syncthreads();

    // ---- coalesced epilogue: y = z0 + alpha * v_bar + yp ----
#pragma unroll
    for (int i = 0; i < 4; ++i) {
        int idx = tid + i * 256;
        int row = idx >> 4;
        int col0 = (idx & 15) * 8;
        float alpha = lds_alpha[row];
        short8 r8 = *reinterpret_cast<const short8*>(
            lds_rho + row * 256 + ((col0 * 2) ^ ((row & 7) << 4)));
        float yv[8];
#pragma unroll
        for (int j = 0; j < 8; ++j) {
            float vb = bf2f((unsigned short)r8[j]);
            yv[j] = ldf<DT>(z0p, col0 + j) + alpha * vb + ldf<DT>(ypp, col0 + j);
        }
        long obase = (row0 + row) * 128 + col0;
        if constexpr (DT == 1) {
            short8 pack;
#pragma unroll
            for (int j = 0; j < 8; ++j) pack[j] = (short)f2bf(yv[j]);
            *reinterpret_cast<short8*>(reinterpret_cast<unsigned short*>(outp) + obase) = pack;
        } else {
            f32x4 p0, p1;
#pragma unroll
            for (int j = 0; j < 4; ++j) { p0[j] = yv[j]; p1[j] = yv[4 + j]; }
            *reinterpret_cast<f32x4*>(reinterpret_cast<float*>(outp) + obase) = p0;
            *reinterpret_cast<f32x4*>(reinterpret_cast<float*>(outp) + obase + 4) = p1;
        }
    }
}

extern "C" void kernel_launch(void* const* d_in, const int* in_sizes, int n_in,
                              void* d_out, int out_size, void* d_ws, size_t ws_size,
                              hipStream_t stream) {
    const void* x    = d_in[0];
    const void* W    = d_in[1];
    const void* b    = d_in[2];
    const void* D    = d_in[3];
    // d_in[4] = NA_E (identity by construction; unused)
    const void* yp   = d_in[5];
    const void* z0   = d_in[6];
    const void* phi  = d_in[7];
    const void* dlt  = d_in[8];
    int* flag = reinterpret_cast<int*>(d_ws);

    const int B = in_sizes[0] / 256;    // 32768
    dim3 grid(B / 64), blk(256);

    detect_dtype<<<dim3(1), dim3(256), 0, stream>>>(
        reinterpret_cast<const unsigned short*>(x), flag);
    rayen_fused<1><<<grid, blk, 0, stream>>>(x, W, b, D, yp, z0, phi, dlt, d_out, flag);
    rayen_fused<0><<<grid, blk, 0, stream>>>(x, W, b, D, yp, z0, phi, dlt, d_out, flag);
}

// Round 4
// 150.304 us; speedup vs baseline: 2.3210x; 2.3080x over previous
//
#include <hip/hip_runtime.h>
#include <hip/hip_bf16.h>

// RAYEN ConstraintModule fused kernel for MI355X (gfx950).
// B=32768, IN_DIM=256, N=K=128, M_LIN=1024, QC=16. bf16 buffers (detector-routed).
// R3: B-operand streaming through LDS double-buffer via global_load_lds (zero VGPR),
// fragment-major LDS layout (zero bank conflicts), counted vmcnt(4) pipeline,
// q-interleaved delta panels (one q per wave -> qsum 16 regs). launch_bounds(256,2).

typedef __attribute__((ext_vector_type(8))) short short8;
typedef __attribute__((ext_vector_type(4))) float f32x4;

__device__ __forceinline__ float bf2f(unsigned short u) {
    union { unsigned int i; float f; } v; v.i = ((unsigned int)u) << 16; return v.f;
}
__device__ __forceinline__ unsigned short f2bf(float f) {
    union { float f; unsigned int i; } v; v.f = f;
    unsigned int r = v.i + 0x7FFFu + ((v.i >> 16) & 1u);  // RNE
    return (unsigned short)(r >> 16);
}

template<int DT>
__device__ __forceinline__ short8 ld8(const void* p, size_t i) {
    if constexpr (DT == 1) {
        return *reinterpret_cast<const short8*>(reinterpret_cast<const unsigned short*>(p) + i);
    } else {
        const float* f = reinterpret_cast<const float*>(p) + i;
        short8 r;
#pragma unroll
        for (int j = 0; j < 8; ++j) r[j] = (short)f2bf(f[j]);
        return r;
    }
}
template<int DT>
__device__ __forceinline__ float ldf(const void* p, int i) {
    if constexpr (DT == 1) return bf2f(reinterpret_cast<const unsigned short*>(p)[i]);
    else return reinterpret_cast<const float*>(p)[i];
}

__device__ __forceinline__ void glds16(const void* g, void* l) {
    __builtin_amdgcn_global_load_lds(
        (const __attribute__((address_space(1))) void*)g,
        (__attribute__((address_space(3))) void*)l, 16, 0, 0);
}

__global__ void detect_dtype(const unsigned short* __restrict__ x, int* __restrict__ flag) {
    __shared__ int cnt;
    if (threadIdx.x == 0) cnt = 0;
    __syncthreads();
    float a = fabsf(bf2f(x[threadIdx.x]));
    int ok = (a > 1e-3f && a < 1e2f) ? 1 : 0;
    atomicAdd(&cnt, ok);
    __syncthreads();
    if (threadIdx.x == 0) *flag = (cnt > 200) ? 1 : 0;  // 1 = bf16, 0 = f32
}

// Stage one 16KB B-panel (64 rows x 256B) in fragment-major order:
// LDS chunk ch (16B): frag f = ch>>6 = w*4+kb, lane l = ch&63 (hi=l>>4, lo=l&15)
// holds global[row(p, w*16+lo)][kb*64 + hi*16 .. +15].
// Panels 0..15: D rows p*64+r. Panels 16..47: delta, q-interleaved:
// row r -> q = (pd>>3)*4 + (r>>4), k_out = (pd&7)*16 + (r&15).
template<int DT>
__device__ __forceinline__ void stage_panel(int p, unsigned char* buf, int tid,
                                            const unsigned char* Db, const unsigned char* Qb) {
#pragma unroll
    for (int i = 0; i < 4; ++i) {
        int ch = i * 256 + tid;
        int r   = ((ch >> 8) << 4) | (ch & 15);                       // panel row 0..63
        int off = (((ch >> 6) & 3) << 6) | (((ch >> 4) & 3) << 4);    // byte 0..255
        int gr; const unsigned char* base;
        if (p < 16) { base = Db; gr = p * 64 + r; }
        else {
            int pd = p - 16;
            base = Qb;
            gr = ((((pd >> 3) << 2) | (r >> 4)) << 7) | (((pd & 7) << 4) | (r & 15));
        }
        if constexpr (DT == 1) {
            glds16(base + (size_t)gr * 256 + off, buf + ch * 16);
        } else {
            short8 v = ld8<0>(base, (size_t)gr * 128 + (off >> 1));
            *reinterpret_cast<short8*>(buf + ch * 16) = v;
        }
    }
}

template<int DT>
__global__ __launch_bounds__(256, 2) void rayen_fused(
    const void* __restrict__ xp,   const void* __restrict__ Wp,
    const void* __restrict__ bp,   const void* __restrict__ Dp,
    const void* __restrict__ ypp,  const void* __restrict__ z0p,
    const void* __restrict__ phip, const void* __restrict__ dltp,
    void* __restrict__ outp,       const int* __restrict__ flag)
{
    if (*flag != DT) return;

    __shared__ unsigned char lds_big[32768];    // x frags; then 2x16KB panel dbuf
    __shared__ unsigned char lds_rho[64 * 256]; // rho [64][256B], XOR3-swizzled rows
    __shared__ float lds_nsq[64][4];
    __shared__ float lds_dmax[64][4];
    __shared__ float lds_quad[64][16];
    __shared__ float lds_lin[64][16];
    __shared__ float lds_alpha[64];

    const int tid = threadIdx.x;
    const int lane = tid & 63;
    const int w = tid >> 6;        // wave 0..3
    const int hi = lane >> 4;      // 0..3
    const int lo = lane & 15;      // 0..15
    const size_t row0 = (size_t)blockIdx.x * 64;

    const unsigned char* Xb = (const unsigned char*)xp;
    const unsigned char* Db = (const unsigned char*)Dp;
    const unsigned char* Qb = (const unsigned char*)dltp;

    // ---- stage x tile [64][256] bf16, fragment-major: frag f = rt*8+kb ----
#pragma unroll
    for (int i = 0; i < 8; ++i) {
        int ch = i * 256 + tid;
        int row = ((ch >> 9) << 4) | (ch & 15);
        int off = (((ch >> 6) & 7) << 6) | (((ch >> 4) & 3) << 4);   // byte in 512B row
        if constexpr (DT == 1)
            glds16(Xb + (row0 + row) * 512 + off, lds_big + ch * 16);
        else {
            short8 v = ld8<0>(Xb, (row0 + row) * 256 + (off >> 1));
            *reinterpret_cast<short8*>(lds_big + ch * 16) = v;
        }
    }

    // W fragments direct to regs (overlaps x staging)
    short8 wf[2][8];
#pragma unroll
    for (int ct = 0; ct < 2; ++ct)
#pragma unroll
        for (int kb = 0; kb < 8; ++kb)
            wf[ct][kb] = ld8<DT>(Wp, (size_t)(w * 32 + ct * 16 + lo) * 256 + kb * 32 + hi * 8);

    asm volatile("s_waitcnt vmcnt(0)" ::: "memory");
    __syncthreads();

    // ---- GEMM1: v[64][128] = x @ W^T; wave w: cols [w*32, w*32+32) ----
    f32x4 acc1[2][4];
#pragma unroll
    for (int c = 0; c < 2; ++c)
#pragma unroll
        for (int r = 0; r < 4; ++r)
#pragma unroll
            for (int e = 0; e < 4; ++e) acc1[c][r][e] = 0.f;

#pragma unroll
    for (int kb = 0; kb < 8; ++kb) {
        short8 af[4];
#pragma unroll
        for (int rt = 0; rt < 4; ++rt)
            af[rt] = *reinterpret_cast<const short8*>(
                lds_big + (((rt << 3) | kb) << 10) + lane * 16);
#pragma unroll
        for (int ct = 0; ct < 2; ++ct)
#pragma unroll
            for (int rt = 0; rt < 4; ++rt)
                acc1[ct][rt] = __builtin_amdgcn_mfma_f32_16x16x32_bf16(af[rt], wf[ct][kb], acc1[ct][rt], 0, 0, 0);
    }

    // bias + per-row sum of squares
    float bv[2];
#pragma unroll
    for (int ct = 0; ct < 2; ++ct) bv[ct] = ldf<DT>(bp, w * 32 + ct * 16 + lo);
#pragma unroll
    for (int rt = 0; rt < 4; ++rt)
#pragma unroll
        for (int reg = 0; reg < 4; ++reg) {
            float s = 0.f;
#pragma unroll
            for (int ct = 0; ct < 2; ++ct) {
                float v = acc1[ct][rt][reg] + bv[ct];
                acc1[ct][rt][reg] = v;
                s += v * v;
            }
            s += __shfl_xor(s, 1);
            s += __shfl_xor(s, 2);
            s += __shfl_xor(s, 4);
            s += __shfl_xor(s, 8);
            if (lo == 0) lds_nsq[rt * 16 + hi * 4 + reg][w] = s;
        }
    __syncthreads();   // x region dead after this point

    // ---- v_bar -> swizzled bf16 rho ----
#pragma unroll
    for (int rt = 0; rt < 4; ++rt)
#pragma unroll
        for (int reg = 0; reg < 4; ++reg) {
            int row = rt * 16 + hi * 4 + reg;
            float nsq = lds_nsq[row][0] + lds_nsq[row][1] + lds_nsq[row][2] + lds_nsq[row][3];
            float rinv = 1.0f / fmaxf(sqrtf(nsq), 1e-12f);
#pragma unroll
            for (int ct = 0; ct < 2; ++ct) {
                int col = w * 32 + ct * 16 + lo;
                unsigned short u = f2bf(acc1[ct][rt][reg] * rinv);
                *reinterpret_cast<unsigned short*>(
                    lds_rho + row * 256 + ((col * 2) ^ ((row & 7) << 4))) = u;
            }
        }
    __syncthreads();

    // ---- A-fragments (rho) resident: 64 VGPRs ----
    short8 af2[4][4];
#pragma unroll
    for (int rt = 0; rt < 4; ++rt)
#pragma unroll
        for (int kb = 0; kb < 4; ++kb) {
            int row = rt * 16 + lo;
            af2[rt][kb] = *reinterpret_cast<const short8*>(
                lds_rho + row * 256 + (((kb << 6) | (hi << 4)) ^ ((lo & 7) << 4)));
        }

    // prime the panel pipeline
    stage_panel<DT>(0, lds_big, tid, Db, Qb);
    stage_panel<DT>(1, lds_big + 16384, tid, Db, Qb);

    f32x4 dmax[4];
#pragma unroll
    for (int rt = 0; rt < 4; ++rt)
#pragma unroll
        for (int e = 0; e < 4; ++e) dmax[rt][e] = -3e38f;
    f32x4 qsum[4];
#pragma unroll
    for (int rt = 0; rt < 4; ++rt)
#pragma unroll
        for (int e = 0; e < 4; ++e) qsum[rt][e] = 0.f;

    // ---- panel loop: 16 D panels + 32 delta panels ----
#pragma unroll 1
    for (int p = 0; p < 48; ++p) {
        if (p < 47) { asm volatile("s_waitcnt vmcnt(4)" ::: "memory"); }
        else        { asm volatile("s_waitcnt vmcnt(0)" ::: "memory"); }
        __syncthreads();

        unsigned char* buf = lds_big + (p & 1) * 16384;
        f32x4 acc[4];
#pragma unroll
        for (int rt = 0; rt < 4; ++rt)
#pragma unroll
            for (int e = 0; e < 4; ++e) acc[rt][e] = 0.f;
#pragma unroll
        for (int kb = 0; kb < 4; ++kb) {
            short8 bf = *reinterpret_cast<const short8*>(
                buf + (((w << 2) | kb) << 10) + lane * 16);
#pragma unroll
            for (int rt = 0; rt < 4; ++rt)
                acc[rt] = __builtin_amdgcn_mfma_f32_16x16x32_bf16(af2[rt][kb], bf, acc[rt], 0, 0, 0);
        }

        if (p < 16) {
#pragma unroll
            for (int rt = 0; rt < 4; ++rt)
#pragma unroll
                for (int e = 0; e < 4; ++e) dmax[rt][e] = fmaxf(dmax[rt][e], acc[rt][e]);
        } else {
            int pd = p - 16;
            int kr = (pd & 7) << 4;
#pragma unroll
            for (int rt = 0; rt < 4; ++rt)
#pragma unroll
                for (int e = 0; e < 4; ++e) {
                    int row = rt * 16 + hi * 4 + e;
                    float rvv = bf2f(*reinterpret_cast<const unsigned short*>(
                        lds_rho + row * 256 + ((((kr + lo) * 2)) ^ ((row & 7) << 4))));
                    qsum[rt][e] += acc[rt][e] * rvv;
                }
            if ((pd & 7) == 7) {
#pragma unroll
                for (int rt = 0; rt < 4; ++rt)
#pragma unroll
                    for (int e = 0; e < 4; ++e) {
                        float s = qsum[rt][e];
                        s += __shfl_xor(s, 1);
                        s += __shfl_xor(s, 2);
                        s += __shfl_xor(s, 4);
                        s += __shfl_xor(s, 8);
                        if (lo == 0) lds_quad[rt * 16 + hi * 4 + e][((pd >> 3) << 2) | w] = s;
                        qsum[rt][e] = 0.f;
                    }
            }
        }
        __syncthreads();
        if (p + 2 < 48) stage_panel<DT>(p + 2, lds_big + (p & 1) * 16384, tid, Db, Qb);
    }

    // ---- dmax reduce ----
#pragma unroll
    for (int rt = 0; rt < 4; ++rt)
#pragma unroll
        for (int reg = 0; reg < 4; ++reg) {
            float m = dmax[rt][reg];
            m = fmaxf(m, __shfl_xor(m, 1));
            m = fmaxf(m, __shfl_xor(m, 2));
            m = fmaxf(m, __shfl_xor(m, 4));
            m = fmaxf(m, __shfl_xor(m, 8));
            if (lo == 0) lds_dmax[rt * 16 + hi * 4 + reg][w] = m;
        }

    // ---- phi (wave 0): lin[b,q] = rho . phi_q ----
    if (w == 0) {
        f32x4 accp[4];
#pragma unroll
        for (int rt = 0; rt < 4; ++rt)
#pragma unroll
            for (int e = 0; e < 4; ++e) accp[rt][e] = 0.f;
#pragma unroll
        for (int kb = 0; kb < 4; ++kb) {
            short8 bp8 = ld8<DT>(phip, (size_t)lo * 128 + kb * 32 + hi * 8);
#pragma unroll
            for (int rt = 0; rt < 4; ++rt)
                accp[rt] = __builtin_amdgcn_mfma_f32_16x16x32_bf16(af2[rt][kb], bp8, accp[rt], 0, 0, 0);
        }
#pragma unroll
        for (int rt = 0; rt < 4; ++rt)
#pragma unroll
            for (int reg = 0; reg < 4; ++reg)
                lds_lin[rt * 16 + hi * 4 + reg][lo] = accp[rt][reg];
    }
    __syncthreads();

    // ---- per-row scalars: kappa, alpha ----
    if (tid < 64) {
        int row = tid;
        float nsq = lds_nsq[row][0] + lds_nsq[row][1] + lds_nsq[row][2] + lds_nsq[row][3];
        float norm = sqrtf(nsq);
        float kap = fmaxf(0.f, fmaxf(fmaxf(lds_dmax[row][0], lds_dmax[row][1]),
                                     fmaxf(lds_dmax[row][2], lds_dmax[row][3])));
#pragma unroll
        for (int q = 0; q < 16; ++q) {
            float kq = lds_lin[row][q] + sqrtf(fmaxf(lds_quad[row][q], 0.f));
            kap = fmaxf(kap, kq);
        }
        lds_alpha[row] = fminf(1.0f / kap, norm);   // kap==0 -> inf -> norm (matches ref)
    }
    __syncthreads();

    // ---- coalesced epilogue: y = z0 + alpha * v_bar + yp (NA_E = I) ----
#pragma unroll
    for (int i = 0; i < 4; ++i) {
        int idx = tid + i * 256;
        int row = idx >> 4;
        int col0 = (idx & 15) * 8;
        float alpha = lds_alpha[row];
        short8 r8 = *reinterpret_cast<const short8*>(
            lds_rho + row * 256 + ((col0 * 2) ^ ((row & 7) << 4)));
        float yv[8];
#pragma unroll
        for (int j = 0; j < 8; ++j) {
            float vb = bf2f((unsigned short)r8[j]);
            yv[j] = ldf<DT>(z0p, col0 + j) + alpha * vb + ldf<DT>(ypp, col0 + j);
        }
        size_t obase = (row0 + row) * 128 + col0;
        if constexpr (DT == 1) {
            short8 pack;
#pragma unroll
            for (int j = 0; j < 8; ++j) pack[j] = (short)f2bf(yv[j]);
            *reinterpret_cast<short8*>(reinterpret_cast<unsigned short*>(outp) + obase) = pack;
        } else {
            f32x4 p0, p1;
#pragma unroll
            for (int j = 0; j < 4; ++j) { p0[j] = yv[j]; p1[j] = yv[4 + j]; }
            *reinterpret_cast<f32x4*>(reinterpret_cast<float*>(outp) + obase) = p0;
            *reinterpret_cast<f32x4*>(reinterpret_cast<float*>(outp) + obase + 4) = p1;
        }
    }
}

extern "C" void kernel_launch(void* const* d_in, const int* in_sizes, int n_in,
                              void* d_out, int out_size, void* d_ws, size_t ws_size,
                              hipStream_t stream) {
    const void* x    = d_in[0];
    const void* W    = d_in[1];
    const void* b    = d_in[2];
    const void* D    = d_in[3];
    // d_in[4] = NA_E (identity by construction; unused)
    const void* yp   = d_in[5];
    const void* z0   = d_in[6];
    const void* phi  = d_in[7];
    const void* dlt  = d_in[8];
    int* flag = reinterpret_cast<int*>(d_ws);

    const int B = in_sizes[0] / 256;    // 32768
    dim3 grid(B / 64), blk(256);

    detect_dtype<<<dim3(1), dim3(256), 0, stream>>>(
        reinterpret_cast<const unsigned short*>(x), flag);
    rayen_fused<1><<<grid, blk, 0, stream>>>(x, W, b, D, yp, z0, phi, dlt, d_out, flag);
    rayen_fused<0><<<grid, blk, 0, stream>>>(x, W, b, D, yp, z0, phi, dlt, d_out, flag);
}